// Round 1
// baseline (67737.543 us; speedup 1.0000x reference)
//
#include <hip/hip_runtime.h>
#include <math.h>

// MPNN: B=32, N=1000, W=4, D=128 -> N_TOTAL=128000 node states of 128 fp32.
// T=2 rounds of (interaction msg+GRU, temporal msg+GRU), then readout MLP.
// All dense layers: thread-owns-row, weights staged in LDS, read as
// wave-uniform broadcasts (conflict-free). Segment-mean via fp32 atomics.

#define DDIM 128
#define NTOT 128000
#define HBYTES 65536000ULL   // 128000*128*4

__device__ __forceinline__ float gelu_exact(float x) {
    // jax.nn.gelu(approximate=False) = 0.5*x*(1+erf(x/sqrt(2)))
    return 0.5f * x * (1.0f + erff(x * 0.70710678118654752440f));
}

__global__ __launch_bounds__(256) void embed_kernel(
    const int* __restrict__ inp, const float* __restrict__ table,
    float* __restrict__ h)
{
    int gid = blockIdx.x * 256 + threadIdx.x;     // over 128000*32 float4s
    if (gid >= NTOT * 32) return;
    int row = gid >> 5;                            // h row = (b*4+w)*1000+n
    int q   = gid & 31;
    int b   = row / 4000;
    int n   = (row % 4000) % 1000;
    int e   = inp[b * 1000 + n];
    ((float4*)h)[gid] = ((const float4*)table)[e * 32 + q];
}

// Message MLP over 2E virtual rows: row<E: x=[h[ni]||h[bi]], seg=bi
//                                   row>=E: x=[h[bi]||h[ni]], seg=ni
__global__ __launch_bounds__(256) void edge_mlp_kernel(
    const float* __restrict__ h,
    const int* __restrict__ ni, const int* __restrict__ bi, int E,
    const float* __restrict__ Win,  const float* __restrict__ bin,
    const float* __restrict__ Whid, const float* __restrict__ bhid,
    const float* __restrict__ Wout, const float* __restrict__ bout,
    float* __restrict__ sbuf, float* __restrict__ cnt)
{
    __shared__ float w[16384];                     // 64 KB, reused per stage
    const int tid = threadIdx.x;
    const int row = blockIdx.x * 256 + tid;
    const bool valid = row < 2 * E;
    int first = 0, second = 0;
    if (valid) {
        if (row < E) { first = ni[row];     second = bi[row];     }
        else         { first = bi[row - E]; second = ni[row - E]; }
    }

    // ---- stage 1: x[256] @ W_in[256x64] + b_in, gelu ----
    for (int i = tid; i < 4096; i += 256)
        ((float4*)w)[i] = ((const float4*)Win)[i];
    __syncthreads();

    float hcur[64];
    #pragma unroll
    for (int j = 0; j < 64; ++j) hcur[j] = bin[j];

    const float4* rowA = (const float4*)(h + (size_t)first  * DDIM);
    const float4* rowB = (const float4*)(h + (size_t)second * DDIM);
    for (int k4 = 0; k4 < 32; ++k4) {
        float4 xv = rowA[k4];
        #pragma unroll
        for (int kk = 0; kk < 4; ++kk) {
            float xk = (&xv.x)[kk];
            const float* wr = &w[(k4 * 4 + kk) * 64];
            #pragma unroll
            for (int j = 0; j < 64; ++j) hcur[j] = fmaf(xk, wr[j], hcur[j]);
        }
    }
    for (int k4 = 0; k4 < 32; ++k4) {
        float4 xv = rowB[k4];
        #pragma unroll
        for (int kk = 0; kk < 4; ++kk) {
            float xk = (&xv.x)[kk];
            const float* wr = &w[(128 + k4 * 4 + kk) * 64];
            #pragma unroll
            for (int j = 0; j < 64; ++j) hcur[j] = fmaf(xk, wr[j], hcur[j]);
        }
    }
    #pragma unroll
    for (int j = 0; j < 64; ++j) hcur[j] = gelu_exact(hcur[j]);

    // ---- 3 hidden layers 64x64 ----
    __syncthreads();
    for (int i = tid; i < 3072; i += 256)
        ((float4*)w)[i] = ((const float4*)Whid)[i];
    __syncthreads();

    for (int L = 0; L < 3; ++L) {
        float acc[64];
        #pragma unroll
        for (int j = 0; j < 64; ++j) acc[j] = bhid[L * 64 + j];
        #pragma unroll
        for (int k = 0; k < 64; ++k) {          // full unroll: hcur[k] const-indexed
            float xk = hcur[k];
            const float* wr = &w[L * 4096 + k * 64];
            #pragma unroll
            for (int j = 0; j < 64; ++j) acc[j] = fmaf(xk, wr[j], acc[j]);
        }
        #pragma unroll
        for (int j = 0; j < 64; ++j) hcur[j] = gelu_exact(acc[j]);
    }

    // ---- output layer 64x128 (two halves), atomic scatter-add ----
    __syncthreads();
    for (int i = tid; i < 2048; i += 256)
        ((float4*)w)[i] = ((const float4*)Wout)[i];
    __syncthreads();

    for (int half = 0; half < 2; ++half) {
        float acc[64];
        #pragma unroll
        for (int j = 0; j < 64; ++j) acc[j] = bout[half * 64 + j];
        #pragma unroll
        for (int k = 0; k < 64; ++k) {
            float xk = hcur[k];
            const float* wr = &w[k * 128 + half * 64];
            #pragma unroll
            for (int j = 0; j < 64; ++j) acc[j] = fmaf(xk, wr[j], acc[j]);
        }
        if (valid) {
            float* dst = sbuf + (size_t)second * DDIM + half * 64;
            #pragma unroll
            for (int j = 0; j < 64; ++j) atomicAdd(&dst[j], acc[j]);
        }
    }
    if (valid) atomicAdd(&cnt[second], 1.0f);
}

// Fused GRU (keras reset_after): hout = z*h + (1-z)*tanh(xh + r*hh)
// One thread per node; d processed in 8 chunks of 16; weights chunk in LDS.
__global__ __launch_bounds__(256) void gru_kernel(
    const float* __restrict__ h, const float* __restrict__ sbuf,
    const float* __restrict__ cnt,
    const float* __restrict__ Wx, const float* __restrict__ Wh,
    const float* __restrict__ bi, const float* __restrict__ br,
    float* __restrict__ hout)
{
    __shared__ float w[12288];   // 6 slices [128][16]: zx, rx, hx, zh, rh, hh
    const int tid  = threadIdx.x;
    const int node = blockIdx.x * 256 + tid;       // grid 500 -> exactly 128000
    const float cinv = 1.0f / fmaxf(cnt[node], 1.0f);
    const float4* mrow = (const float4*)(sbuf + (size_t)node * DDIM);
    const float4* hrow = (const float4*)(h    + (size_t)node * DDIM);

    for (int c = 0; c < 8; ++c) {
        const int d0 = c * 16;
        for (int i = tid; i < 2048; i += 256) {
            int k = i >> 4, dd = i & 15;
            w[i]         = Wx[k * 384 +       d0 + dd];
            w[2048 + i]  = Wx[k * 384 + 128 + d0 + dd];
            w[4096 + i]  = Wx[k * 384 + 256 + d0 + dd];
            w[6144 + i]  = Wh[k * 384 +       d0 + dd];
            w[8192 + i]  = Wh[k * 384 + 128 + d0 + dd];
            w[10240 + i] = Wh[k * 384 + 256 + d0 + dd];
        }
        __syncthreads();

        float az[16], ar[16], axh[16], ahh[16];
        #pragma unroll
        for (int dd = 0; dd < 16; ++dd) {
            az[dd]  = bi[d0 + dd]       + br[d0 + dd];
            ar[dd]  = bi[128 + d0 + dd] + br[128 + d0 + dd];
            axh[dd] = bi[256 + d0 + dd];
            ahh[dd] = br[256 + d0 + dd];
        }
        for (int k4 = 0; k4 < 32; ++k4) {
            float4 m4 = mrow[k4];
            float4 h4 = hrow[k4];
            #pragma unroll
            for (int kk = 0; kk < 4; ++kk) {
                float mv = (&m4.x)[kk] * cinv;
                float hv = (&h4.x)[kk];
                const int kb = (k4 * 4 + kk) * 16;
                #pragma unroll
                for (int dd = 0; dd < 16; ++dd) {
                    az[dd]  = fmaf(mv, w[kb + dd],          az[dd]);
                    az[dd]  = fmaf(hv, w[6144 + kb + dd],   az[dd]);
                    ar[dd]  = fmaf(mv, w[2048 + kb + dd],   ar[dd]);
                    ar[dd]  = fmaf(hv, w[8192 + kb + dd],   ar[dd]);
                    axh[dd] = fmaf(mv, w[4096 + kb + dd],  axh[dd]);
                    ahh[dd] = fmaf(hv, w[10240 + kb + dd], ahh[dd]);
                }
            }
        }
        float4 hv4[4];
        #pragma unroll
        for (int q = 0; q < 4; ++q) hv4[q] = hrow[c * 4 + q];
        float4 o[4];
        #pragma unroll
        for (int dd = 0; dd < 16; ++dd) {
            float z    = 1.0f / (1.0f + expf(-az[dd]));
            float r    = 1.0f / (1.0f + expf(-ar[dd]));
            float cand = tanhf(axh[dd] + r * ahh[dd]);
            float hval = (&hv4[dd >> 2].x)[dd & 3];
            (&o[dd >> 2].x)[dd & 3] = z * hval + (1.0f - z) * cand;
        }
        float4* orow = (float4*)(hout + (size_t)node * DDIM + d0);
        #pragma unroll
        for (int q = 0; q < 4; ++q) orow[q] = o[q];
        __syncthreads();
    }
}

__global__ __launch_bounds__(256) void readout_kernel(
    const float* __restrict__ h,
    const float* __restrict__ Win,  const float* __restrict__ bin,
    const float* __restrict__ Whid, const float* __restrict__ bhid,
    const float* __restrict__ Wout, const float* __restrict__ bout,
    float* __restrict__ out)
{
    __shared__ float w[12288];
    const int tid = threadIdx.x;
    const int row = blockIdx.x * 256 + tid;        // 0..31999 exactly
    const int b = row / 1000, n = row % 1000;
    const float4* xrow = (const float4*)(h + ((size_t)b * 4000 + n) * DDIM);

    for (int i = tid; i < 2048; i += 256)
        ((float4*)w)[i] = ((const float4*)Win)[i];
    __syncthreads();

    float hcur[64];
    #pragma unroll
    for (int j = 0; j < 64; ++j) hcur[j] = bin[j];
    for (int k4 = 0; k4 < 32; ++k4) {
        float4 xv = xrow[k4];
        #pragma unroll
        for (int kk = 0; kk < 4; ++kk) {
            float xk = (&xv.x)[kk];
            const float* wr = &w[(k4 * 4 + kk) * 64];
            #pragma unroll
            for (int j = 0; j < 64; ++j) hcur[j] = fmaf(xk, wr[j], hcur[j]);
        }
    }
    #pragma unroll
    for (int j = 0; j < 64; ++j) hcur[j] = gelu_exact(hcur[j]);

    __syncthreads();
    for (int i = tid; i < 3072; i += 256)
        ((float4*)w)[i] = ((const float4*)Whid)[i];
    __syncthreads();

    for (int L = 0; L < 3; ++L) {
        float acc[64];
        #pragma unroll
        for (int j = 0; j < 64; ++j) acc[j] = bhid[L * 64 + j];
        #pragma unroll
        for (int k = 0; k < 64; ++k) {
            float xk = hcur[k];
            const float* wr = &w[L * 4096 + k * 64];
            #pragma unroll
            for (int j = 0; j < 64; ++j) acc[j] = fmaf(xk, wr[j], acc[j]);
        }
        #pragma unroll
        for (int j = 0; j < 64; ++j) hcur[j] = gelu_exact(acc[j]);
    }

    __syncthreads();
    for (int i = tid; i < 640; i += 256) w[i] = Wout[i];
    __syncthreads();

    float acc[10];
    #pragma unroll
    for (int p = 0; p < 10; ++p) acc[p] = bout[p];
    #pragma unroll
    for (int k = 0; k < 64; ++k) {
        float xk = hcur[k];
        #pragma unroll
        for (int p = 0; p < 10; ++p) acc[p] = fmaf(xk, w[k * 10 + p], acc[p]);
    }
    #pragma unroll
    for (int p = 0; p < 10; ++p) out[(size_t)row * 10 + p] = acc[p];
}

extern "C" void kernel_launch(void* const* d_in, const int* in_sizes, int n_in,
                              void* d_out, int out_size, void* d_ws, size_t ws_size,
                              hipStream_t stream) {
    const int*   node_inputs = (const int*)d_in[0];
    const int*   ni_int = (const int*)d_in[1];
    const int*   bi_int = (const int*)d_in[2];
    const int*   ni_tmp = (const int*)d_in[3];
    const int*   bi_tmp = (const int*)d_in[4];
    const float* embed  = (const float*)d_in[5];
    const float* mWin   = (const float*)d_in[6];
    const float* mbin   = (const float*)d_in[7];
    const float* mWhid  = (const float*)d_in[8];
    const float* mbhid  = (const float*)d_in[9];
    const float* mWout  = (const float*)d_in[10];
    const float* mbout  = (const float*)d_in[11];
    const float* roWin  = (const float*)d_in[12];
    const float* robin  = (const float*)d_in[13];
    const float* roWhid = (const float*)d_in[14];
    const float* robhid = (const float*)d_in[15];
    const float* roWout = (const float*)d_in[16];
    const float* robout = (const float*)d_in[17];
    const float* giWx = (const float*)d_in[18];
    const float* giWh = (const float*)d_in[19];
    const float* gibi = (const float*)d_in[20];
    const float* gibr = (const float*)d_in[21];
    const float* gtWx = (const float*)d_in[22];
    const float* gtWh = (const float*)d_in[23];
    const float* gtbi = (const float*)d_in[24];
    const float* gtbr = (const float*)d_in[25];
    float* out = (float*)d_out;

    char* ws = (char*)d_ws;
    float* hA   = (float*)(ws);
    float* hB   = (float*)(ws + HBYTES);
    float* sbuf = (float*)(ws + 2 * HBYTES);
    float* cbuf = (float*)(ws + 3 * HBYTES);   // 128000 floats

    embed_kernel<<<16000, 256, 0, stream>>>(node_inputs, embed, hA);

    float* hc = hA;
    float* hn = hB;
    for (int t = 0; t < 2; ++t) {
        // interaction phase
        hipMemsetAsync(sbuf, 0, HBYTES, stream);
        hipMemsetAsync(cbuf, 0, NTOT * sizeof(float), stream);
        edge_mlp_kernel<<<(2 * 200000 + 255) / 256, 256, 0, stream>>>(
            hc, ni_int, bi_int, 200000,
            mWin, mbin, mWhid, mbhid, mWout, mbout, sbuf, cbuf);
        gru_kernel<<<NTOT / 256, 256, 0, stream>>>(
            hc, sbuf, cbuf, giWx, giWh, gibi, gibr, hn);
        { float* tmp = hc; hc = hn; hn = tmp; }

        // temporal phase
        hipMemsetAsync(sbuf, 0, HBYTES, stream);
        hipMemsetAsync(cbuf, 0, NTOT * sizeof(float), stream);
        edge_mlp_kernel<<<(2 * 96000 + 255) / 256, 256, 0, stream>>>(
            hc, ni_tmp, bi_tmp, 96000,
            mWin, mbin, mWhid, mbhid, mWout, mbout, sbuf, cbuf);
        gru_kernel<<<NTOT / 256, 256, 0, stream>>>(
            hc, sbuf, cbuf, gtWx, gtWh, gtbi, gtbr, hn);
        { float* tmp = hc; hc = hn; hn = tmp; }
    }

    readout_kernel<<<32000 / 256, 256, 0, stream>>>(
        hc, roWin, robin, roWhid, robhid, roWout, robout, out);
}

// Round 2
// 44871.210 us; speedup vs baseline: 1.5096x; 1.5096x over previous
//
#include <hip/hip_runtime.h>
#include <math.h>

// MPNN: B=32, N=1000, W=4, D=128 -> N_TOTAL=128000 node states of 128 fp32.
// T=2 rounds of (interaction msg+GRU, temporal msg+GRU), then readout MLP.
// Edge MLP: thread-owns-row compute (weights broadcast from LDS, chunked
// 16KB stages), gather prefetched ahead of staging barriers, segment-sum
// scatter COALESCED via per-wave LDS transpose (stride-65 padding) ->
// 64-lane consecutive atomics (4 lines/instr instead of 64).
// Segment counts hoisted to a once-per-launch kernel (reused across T).

#define DDIM 128
#define NTOT 128000
#define HBYTES 65536000ULL   // 128000*128*4

__device__ __forceinline__ float gelu_exact(float x) {
    // jax.nn.gelu(approximate=False) = 0.5*x*(1+erf(x/sqrt(2)))
    return 0.5f * x * (1.0f + erff(x * 0.70710678118654752440f));
}

__global__ __launch_bounds__(256) void embed_kernel(
    const int* __restrict__ inp, const float* __restrict__ table,
    float* __restrict__ h)
{
    int gid = blockIdx.x * 256 + threadIdx.x;     // over 128000*32 float4s
    if (gid >= NTOT * 32) return;
    int row = gid >> 5;                            // h row = (b*4+w)*1000+n
    int q   = gid & 31;
    int b   = row / 4000;
    int n   = (row % 4000) % 1000;
    int e   = inp[b * 1000 + n];
    ((float4*)h)[gid] = ((const float4*)table)[e * 32 + q];
}

// Segment counts (constant across the T loop): seg = concat(bi, ni).
__global__ __launch_bounds__(256) void count_kernel(
    const int* __restrict__ ni, const int* __restrict__ bi, int E,
    float* __restrict__ cnt)
{
    int g = blockIdx.x * 256 + threadIdx.x;
    if (g < E)          atomicAdd(&cnt[bi[g]], 1.0f);
    else if (g < 2 * E) atomicAdd(&cnt[ni[g - E]], 1.0f);
}

// Message MLP over 2E virtual rows: row<E: x=[h[ni]||h[bi]], seg=bi
//                                   row>=E: x=[h[bi]||h[ni]], seg=ni
__global__ __launch_bounds__(256, 3) void edge_mlp_kernel(
    const float* __restrict__ h,
    const int* __restrict__ ni, const int* __restrict__ bi, int E,
    const float* __restrict__ Win,  const float* __restrict__ bin,
    const float* __restrict__ Whid, const float* __restrict__ bhid,
    const float* __restrict__ Wout, const float* __restrict__ bout,
    float* __restrict__ sbuf)
{
    __shared__ float w[4096];         // 16KB: current weight chunk
    __shared__ float scat[4][1040];   // 16.6KB: per-wave 16x(64+pad) transpose
    const int tid  = threadIdx.x;
    const int lane = tid & 63;
    const int wv   = tid >> 6;
    const int row  = blockIdx.x * 256 + tid;
    const bool valid = row < 2 * E;
    int first = 0, second = 0;
    if (valid) {
        if (row < E) { first = ni[row];     second = bi[row];     }
        else         { first = bi[row - E]; second = ni[row - E]; }
    }
    const int segv = valid ? second : -1;

    const float* rowp0 = h + (size_t)first  * DDIM;
    const float* rowp1 = h + (size_t)second * DDIM;

    // ---- stage 1: x[256] @ W_in[256x64] + b_in, gelu; W_in in 4 chunks ----
    float hcur[64];
    #pragma unroll
    for (int j = 0; j < 64; ++j) hcur[j] = bin[j];

    for (int c = 0; c < 4; ++c) {
        const float4* xb = (const float4*)((c < 2) ? rowp0 : rowp1) + (c & 1) * 16;
        float4 xv[8];
        #pragma unroll
        for (int q = 0; q < 8; ++q) xv[q] = xb[q];   // in flight across staging
        __syncthreads();
        for (int i4 = tid; i4 < 1024; i4 += 256)
            ((float4*)w)[i4] = ((const float4*)(Win + c * 4096))[i4];
        __syncthreads();
        #pragma unroll
        for (int q = 0; q < 8; ++q) {
            #pragma unroll
            for (int kk = 0; kk < 4; ++kk) {
                const float xk = (&xv[q].x)[kk];
                const float* wr = &w[(q * 4 + kk) * 64];
                #pragma unroll
                for (int j = 0; j < 64; ++j) hcur[j] = fmaf(xk, wr[j], hcur[j]);
            }
        }
        #pragma unroll
        for (int q = 0; q < 8; ++q) xv[q] = xb[8 + q];
        #pragma unroll
        for (int q = 0; q < 8; ++q) {
            #pragma unroll
            for (int kk = 0; kk < 4; ++kk) {
                const float xk = (&xv[q].x)[kk];
                const float* wr = &w[(32 + q * 4 + kk) * 64];
                #pragma unroll
                for (int j = 0; j < 64; ++j) hcur[j] = fmaf(xk, wr[j], hcur[j]);
            }
        }
    }
    #pragma unroll
    for (int j = 0; j < 64; ++j) hcur[j] = gelu_exact(hcur[j]);

    // ---- 3 hidden layers 64x64, one 16KB stage each ----
    for (int L = 0; L < 3; ++L) {
        __syncthreads();
        for (int i4 = tid; i4 < 1024; i4 += 256)
            ((float4*)w)[i4] = ((const float4*)(Whid + L * 4096))[i4];
        __syncthreads();
        float acc[64];
        #pragma unroll
        for (int j = 0; j < 64; ++j) acc[j] = bhid[L * 64 + j];
        #pragma unroll
        for (int k = 0; k < 64; ++k) {
            const float xk = hcur[k];
            const float* wr = &w[k * 64];
            #pragma unroll
            for (int j = 0; j < 64; ++j) acc[j] = fmaf(xk, wr[j], acc[j]);
        }
        #pragma unroll
        for (int j = 0; j < 64; ++j) hcur[j] = gelu_exact(acc[j]);
    }

    // ---- output layer 64x128 in two 64-col halves + coalesced scatter ----
    for (int half = 0; half < 2; ++half) {
        __syncthreads();
        for (int i4 = tid; i4 < 1024; i4 += 256) {
            int k = i4 >> 4, jq = i4 & 15;
            ((float4*)w)[i4] = *(const float4*)(Wout + k * 128 + half * 64 + jq * 4);
        }
        __syncthreads();
        float acc[64];
        #pragma unroll
        for (int j = 0; j < 64; ++j) acc[j] = bout[half * 64 + j];
        #pragma unroll
        for (int k = 0; k < 64; ++k) {
            const float xk = hcur[k];
            const float* wr = &w[k * 64];
            #pragma unroll
            for (int j = 0; j < 64; ++j) acc[j] = fmaf(xk, wr[j], acc[j]);
        }
        // transpose 16 rows at a time per wave through padded LDS, then
        // 64 lanes atomicAdd 64 consecutive floats of one segment row
        for (int sub = 0; sub < 4; ++sub) {
            __syncthreads();                       // region reuse guard
            if ((lane >> 4) == sub) {
                float* dp = &scat[wv][(lane & 15) * 65];
                #pragma unroll
                for (int j = 0; j < 64; ++j) dp[j] = acc[j];
            }
            __syncthreads();
            for (int r = 0; r < 16; ++r) {
                const int seg = __shfl(segv, sub * 16 + r);
                if (seg >= 0) {
                    atomicAdd(sbuf + (size_t)seg * DDIM + half * 64 + lane,
                              scat[wv][r * 65 + lane]);
                }
            }
        }
    }
}

// Fused GRU (keras reset_after): hout = z*h + (1-z)*tanh(xh + r*hh)
__global__ __launch_bounds__(256) void gru_kernel(
    const float* __restrict__ h, const float* __restrict__ sbuf,
    const float* __restrict__ cnt,
    const float* __restrict__ Wx, const float* __restrict__ Wh,
    const float* __restrict__ bi, const float* __restrict__ br,
    float* __restrict__ hout)
{
    __shared__ float w[12288];   // 6 slices [128][16]: zx, rx, hx, zh, rh, hh
    const int tid  = threadIdx.x;
    const int node = blockIdx.x * 256 + tid;       // grid 500 -> exactly 128000
    const float cinv = 1.0f / fmaxf(cnt[node], 1.0f);
    const float4* mrow = (const float4*)(sbuf + (size_t)node * DDIM);
    const float4* hrow = (const float4*)(h    + (size_t)node * DDIM);

    for (int c = 0; c < 8; ++c) {
        const int d0 = c * 16;
        for (int i = tid; i < 2048; i += 256) {
            int k = i >> 4, dd = i & 15;
            w[i]         = Wx[k * 384 +       d0 + dd];
            w[2048 + i]  = Wx[k * 384 + 128 + d0 + dd];
            w[4096 + i]  = Wx[k * 384 + 256 + d0 + dd];
            w[6144 + i]  = Wh[k * 384 +       d0 + dd];
            w[8192 + i]  = Wh[k * 384 + 128 + d0 + dd];
            w[10240 + i] = Wh[k * 384 + 256 + d0 + dd];
        }
        __syncthreads();

        float az[16], ar[16], axh[16], ahh[16];
        #pragma unroll
        for (int dd = 0; dd < 16; ++dd) {
            az[dd]  = bi[d0 + dd]       + br[d0 + dd];
            ar[dd]  = bi[128 + d0 + dd] + br[128 + d0 + dd];
            axh[dd] = bi[256 + d0 + dd];
            ahh[dd] = br[256 + d0 + dd];
        }
        for (int k4 = 0; k4 < 32; ++k4) {
            float4 m4 = mrow[k4];
            float4 h4 = hrow[k4];
            #pragma unroll
            for (int kk = 0; kk < 4; ++kk) {
                float mv = (&m4.x)[kk] * cinv;
                float hv = (&h4.x)[kk];
                const int kb = (k4 * 4 + kk) * 16;
                #pragma unroll
                for (int dd = 0; dd < 16; ++dd) {
                    az[dd]  = fmaf(mv, w[kb + dd],          az[dd]);
                    az[dd]  = fmaf(hv, w[6144 + kb + dd],   az[dd]);
                    ar[dd]  = fmaf(mv, w[2048 + kb + dd],   ar[dd]);
                    ar[dd]  = fmaf(hv, w[8192 + kb + dd],   ar[dd]);
                    axh[dd] = fmaf(mv, w[4096 + kb + dd],  axh[dd]);
                    ahh[dd] = fmaf(hv, w[10240 + kb + dd], ahh[dd]);
                }
            }
        }
        float4 hv4[4];
        #pragma unroll
        for (int q = 0; q < 4; ++q) hv4[q] = hrow[c * 4 + q];
        float4 o[4];
        #pragma unroll
        for (int dd = 0; dd < 16; ++dd) {
            float z    = 1.0f / (1.0f + expf(-az[dd]));
            float r    = 1.0f / (1.0f + expf(-ar[dd]));
            float cand = tanhf(axh[dd] + r * ahh[dd]);
            float hval = (&hv4[dd >> 2].x)[dd & 3];
            (&o[dd >> 2].x)[dd & 3] = z * hval + (1.0f - z) * cand;
        }
        float4* orow = (float4*)(hout + (size_t)node * DDIM + d0);
        #pragma unroll
        for (int q = 0; q < 4; ++q) orow[q] = o[q];
        __syncthreads();
    }
}

__global__ __launch_bounds__(256) void readout_kernel(
    const float* __restrict__ h,
    const float* __restrict__ Win,  const float* __restrict__ bin,
    const float* __restrict__ Whid, const float* __restrict__ bhid,
    const float* __restrict__ Wout, const float* __restrict__ bout,
    float* __restrict__ out)
{
    __shared__ float w[12288];
    const int tid = threadIdx.x;
    const int row = blockIdx.x * 256 + tid;        // 0..31999 exactly
    const int b = row / 1000, n = row % 1000;
    const float4* xrow = (const float4*)(h + ((size_t)b * 4000 + n) * DDIM);

    for (int i = tid; i < 2048; i += 256)
        ((float4*)w)[i] = ((const float4*)Win)[i];
    __syncthreads();

    float hcur[64];
    #pragma unroll
    for (int j = 0; j < 64; ++j) hcur[j] = bin[j];
    for (int k4 = 0; k4 < 32; ++k4) {
        float4 xv = xrow[k4];
        #pragma unroll
        for (int kk = 0; kk < 4; ++kk) {
            float xk = (&xv.x)[kk];
            const float* wr = &w[(k4 * 4 + kk) * 64];
            #pragma unroll
            for (int j = 0; j < 64; ++j) hcur[j] = fmaf(xk, wr[j], hcur[j]);
        }
    }
    #pragma unroll
    for (int j = 0; j < 64; ++j) hcur[j] = gelu_exact(hcur[j]);

    __syncthreads();
    for (int i = tid; i < 3072; i += 256)
        ((float4*)w)[i] = ((const float4*)Whid)[i];
    __syncthreads();

    for (int L = 0; L < 3; ++L) {
        float acc[64];
        #pragma unroll
        for (int j = 0; j < 64; ++j) acc[j] = bhid[L * 64 + j];
        #pragma unroll
        for (int k = 0; k < 64; ++k) {
            float xk = hcur[k];
            const float* wr = &w[L * 4096 + k * 64];
            #pragma unroll
            for (int j = 0; j < 64; ++j) acc[j] = fmaf(xk, wr[j], acc[j]);
        }
        #pragma unroll
        for (int j = 0; j < 64; ++j) hcur[j] = gelu_exact(acc[j]);
    }

    __syncthreads();
    for (int i = tid; i < 640; i += 256) w[i] = Wout[i];
    __syncthreads();

    float acc[10];
    #pragma unroll
    for (int p = 0; p < 10; ++p) acc[p] = bout[p];
    #pragma unroll
    for (int k = 0; k < 64; ++k) {
        float xk = hcur[k];
        #pragma unroll
        for (int p = 0; p < 10; ++p) acc[p] = fmaf(xk, w[k * 10 + p], acc[p]);
    }
    #pragma unroll
    for (int p = 0; p < 10; ++p) out[(size_t)row * 10 + p] = acc[p];
}

extern "C" void kernel_launch(void* const* d_in, const int* in_sizes, int n_in,
                              void* d_out, int out_size, void* d_ws, size_t ws_size,
                              hipStream_t stream) {
    const int*   node_inputs = (const int*)d_in[0];
    const int*   ni_int = (const int*)d_in[1];
    const int*   bi_int = (const int*)d_in[2];
    const int*   ni_tmp = (const int*)d_in[3];
    const int*   bi_tmp = (const int*)d_in[4];
    const float* embed  = (const float*)d_in[5];
    const float* mWin   = (const float*)d_in[6];
    const float* mbin   = (const float*)d_in[7];
    const float* mWhid  = (const float*)d_in[8];
    const float* mbhid  = (const float*)d_in[9];
    const float* mWout  = (const float*)d_in[10];
    const float* mbout  = (const float*)d_in[11];
    const float* roWin  = (const float*)d_in[12];
    const float* robin  = (const float*)d_in[13];
    const float* roWhid = (const float*)d_in[14];
    const float* robhid = (const float*)d_in[15];
    const float* roWout = (const float*)d_in[16];
    const float* robout = (const float*)d_in[17];
    const float* giWx = (const float*)d_in[18];
    const float* giWh = (const float*)d_in[19];
    const float* gibi = (const float*)d_in[20];
    const float* gibr = (const float*)d_in[21];
    const float* gtWx = (const float*)d_in[22];
    const float* gtWh = (const float*)d_in[23];
    const float* gtbi = (const float*)d_in[24];
    const float* gtbr = (const float*)d_in[25];
    float* out = (float*)d_out;

    char* ws = (char*)d_ws;
    float* hA      = (float*)(ws);
    float* hB      = (float*)(ws + HBYTES);
    float* sbuf    = (float*)(ws + 2 * HBYTES);
    float* cnt_int = (float*)(ws + 3 * HBYTES);
    float* cnt_tmp = (float*)(ws + 3 * HBYTES + NTOT * sizeof(float));

    const int E_INT = 200000, E_TMP = 96000;

    embed_kernel<<<16000, 256, 0, stream>>>(node_inputs, embed, hA);

    hipMemsetAsync(cnt_int, 0, NTOT * sizeof(float), stream);
    hipMemsetAsync(cnt_tmp, 0, NTOT * sizeof(float), stream);
    count_kernel<<<(2 * E_INT + 255) / 256, 256, 0, stream>>>(ni_int, bi_int, E_INT, cnt_int);
    count_kernel<<<(2 * E_TMP + 255) / 256, 256, 0, stream>>>(ni_tmp, bi_tmp, E_TMP, cnt_tmp);

    float* hc = hA;
    float* hn = hB;
    for (int t = 0; t < 2; ++t) {
        // interaction phase
        hipMemsetAsync(sbuf, 0, HBYTES, stream);
        edge_mlp_kernel<<<(2 * E_INT + 255) / 256, 256, 0, stream>>>(
            hc, ni_int, bi_int, E_INT,
            mWin, mbin, mWhid, mbhid, mWout, mbout, sbuf);
        gru_kernel<<<NTOT / 256, 256, 0, stream>>>(
            hc, sbuf, cnt_int, giWx, giWh, gibi, gibr, hn);
        { float* tmp = hc; hc = hn; hn = tmp; }

        // temporal phase
        hipMemsetAsync(sbuf, 0, HBYTES, stream);
        edge_mlp_kernel<<<(2 * E_TMP + 255) / 256, 256, 0, stream>>>(
            hc, ni_tmp, bi_tmp, E_TMP,
            mWin, mbin, mWhid, mbhid, mWout, mbout, sbuf);
        gru_kernel<<<NTOT / 256, 256, 0, stream>>>(
            hc, sbuf, cnt_tmp, gtWx, gtWh, gtbi, gtbr, hn);
        { float* tmp = hc; hc = hn; hn = tmp; }
    }

    readout_kernel<<<32000 / 256, 256, 0, stream>>>(
        hc, roWin, robin, roWhid, robhid, roWout, robout, out);
}